// Round 4
// baseline (587.194 us; speedup 1.0000x reference)
//
#include <hip/hip_runtime.h>
#include <cmath>

#define B_ 128
#define L_ 128
#define N_ 16
#define E_ 128
#define D_ 128
#define H_ 100
#define G_ 300   // 3*H
#define C_ 104
#define T_ (B_*L_)

// ---------------------------------------------------------------------------
// K1: fused embedding gather + W_c projection + bottom-up tree aggregation +
//     node max-pool + relu  ->  enc[T, D]
// One d-column per thread (128 threads), Wc row in registers, emb in LDS
// (broadcast reads). Tree aggregation is column-independent (no barriers).
// ---------------------------------------------------------------------------
__global__ __launch_bounds__(128) void k_tree(
    const int* __restrict__ tokens, const int* __restrict__ parents,
    const float* __restrict__ emb, const float* __restrict__ Wc_w,
    const float* __restrict__ Wc_b, float* __restrict__ enc) {
  __shared__ __align__(16) float s_emb[N_][E_];
  __shared__ int s_tok[N_], s_par[N_];
  const int d = threadIdx.x;

  // Wc row d -> 32 float4 registers (one-time, reused across all trees)
  float4 w[32];
  const float4* wc4 = reinterpret_cast<const float4*>(Wc_w + (size_t)d * E_);
#pragma unroll
  for (int i = 0; i < 32; ++i) w[i] = wc4[i];
  const float bias = Wc_b[d];

  for (int t = blockIdx.x; t < T_; t += gridDim.x) {
    __syncthreads();  // safe reuse of s_emb from previous tree
    if (d < N_) {
      s_tok[d] = tokens[t * N_ + d];
      s_par[d] = parents[t * N_ + d];
    }
    __syncthreads();
    // stage 16 embedding rows (coalesced 512B per row)
#pragma unroll
    for (int j = 0; j < N_; ++j)
      s_emb[j][d] = emb[(size_t)s_tok[j] * E_ + d];
    __syncthreads();

    // g[j][d] = dot(emb_row_j, Wc[d]) + bias   (broadcast float4 LDS reads)
    float acc[N_];
#pragma unroll
    for (int j = 0; j < N_; ++j) acc[j] = bias;
#pragma unroll
    for (int e0 = 0; e0 < 32; ++e0) {
      const float4 wv = w[e0];
#pragma unroll
      for (int j = 0; j < N_; ++j) {
        const float4 m = reinterpret_cast<const float4*>(&s_emb[j][0])[e0];
        acc[j] += m.x * wv.x + m.y * wv.y + m.z * wv.z + m.w * wv.w;
      }
    }
    __syncthreads();  // everyone done READING s_emb before we overwrite it

    // write node values into LDS column d, aggregate bottom-up, then max
#pragma unroll
    for (int j = 0; j < N_; ++j) s_emb[j][d] = acc[j];
#pragma unroll
    for (int j = N_ - 1; j >= 1; --j) {
      const int p = s_par[j];          // uniform; p < j guaranteed
      s_emb[p][d] += s_emb[j][d];      // column-local, no cross-thread dep
    }
    float mv = s_emb[0][d];
#pragma unroll
    for (int j = 1; j < N_; ++j) mv = fmaxf(mv, s_emb[j][d]);
    enc[(size_t)t * D_ + d] = fmaxf(mv, 0.0f);
  }
}

// ---------------------------------------------------------------------------
// K2: GRU input projections for BOTH directions:
//     xW{f,b}[l][b][g] = dot(enc[b][l][:], Wih[g][:]) + bih[g]
// thread = g (600 rows across two dirs), Wih row in registers, 8 enc rows/block
// ---------------------------------------------------------------------------
__global__ __launch_bounds__(640) void k_xw(
    const float* __restrict__ enc,
    const float* __restrict__ Wih_f, const float* __restrict__ bih_f,
    const float* __restrict__ Wih_b, const float* __restrict__ bih_b,
    float* __restrict__ xWf, float* __restrict__ xWb) {
  __shared__ __align__(16) float s_enc[8][D_];
  const int tid = threadIdx.x;
  const int m0 = blockIdx.x * 8;

  for (int i = tid; i < 8 * D_; i += 640)
    s_enc[i >> 7][i & 127] = enc[(size_t)m0 * D_ + i];

  float4 w[32];
  float bias = 0.f;
  const int g = tid;
  if (g < 2 * G_) {
    const float* Wrow =
        (g < G_) ? (Wih_f + (size_t)g * D_) : (Wih_b + (size_t)(g - G_) * D_);
    const float4* w4 = reinterpret_cast<const float4*>(Wrow);
#pragma unroll
    for (int i = 0; i < 32; ++i) w[i] = w4[i];
    bias = (g < G_) ? bih_f[g] : bih_b[g - G_];
  }
  __syncthreads();
  if (g >= 2 * G_) return;

  float* const dst = (g < G_) ? xWf : xWb;
  const int gg = (g < G_) ? g : g - G_;
#pragma unroll
  for (int mi = 0; mi < 8; ++mi) {
    float a0 = bias, a1 = 0.f;
#pragma unroll
    for (int e0 = 0; e0 < 32; ++e0) {
      const float4 m4 = reinterpret_cast<const float4*>(&s_enc[mi][0])[e0];
      const float4 wv = w[e0];
      a0 += m4.x * wv.x + m4.z * wv.z;
      a1 += m4.y * wv.y + m4.w * wv.w;
    }
    const int m = m0 + mi;
    const int b = m >> 7, l = m & 127;  // m = b*L + l
    dst[((size_t)l * B_ + b) * G_ + gg] = a0 + a1;
  }
}

// ---------------------------------------------------------------------------
// K3: sequential GRU scan, one block per (dir, batch) -> 256 blocks (full chip)
// Whh row in registers; h double-buffered in LDS; running time-max in regs.
// ---------------------------------------------------------------------------
__global__ __launch_bounds__(320) void k_gru(
    const float* __restrict__ xWf, const float* __restrict__ xWb,
    const float* __restrict__ Whh_f, const float* __restrict__ bhh_f,
    const float* __restrict__ Whh_b, const float* __restrict__ bhh_b,
    float* __restrict__ pooled) {
  const int tid = threadIdx.x;
  const int dir = blockIdx.x >> 7;
  const int b = blockIdx.x & 127;
  const float* xW = dir ? xWb : xWf;
  const float* Whh = dir ? Whh_b : Whh_f;
  const float* bhh = dir ? bhh_b : bhh_f;

  __shared__ float s_h[2][H_];
  __shared__ float s_hW[G_];
  __shared__ float s_x[G_];

  float4 w[25];
  float bias = 0.f;
  if (tid < G_) {
    const float4* w4 = reinterpret_cast<const float4*>(Whh + (size_t)tid * H_);
#pragma unroll
    for (int i = 0; i < 25; ++i) w[i] = w4[i];
    bias = bhh[tid];
  }
  if (tid < H_) s_h[0][tid] = 0.f;
  float hmax = -1e30f;
  __syncthreads();

  for (int t = 0; t < L_; ++t) {
    const int tt = dir ? (L_ - 1 - t) : t;
    const int cur = t & 1, nxt = cur ^ 1;
    if (tid < G_) {
      const float x = xW[((size_t)tt * B_ + b) * G_ + tid];  // issue early
      float a0 = bias, a1 = 0.f;
#pragma unroll
      for (int k = 0; k < 25; ++k) {
        const float4 wv = w[k];
        a0 += s_h[cur][4 * k + 0] * wv.x + s_h[cur][4 * k + 2] * wv.z;
        a1 += s_h[cur][4 * k + 1] * wv.y + s_h[cur][4 * k + 3] * wv.w;
      }
      s_hW[tid] = a0 + a1;
      s_x[tid] = x;
    }
    __syncthreads();
    if (tid < H_) {
      const float xr = s_x[tid], xz = s_x[tid + H_], xn = s_x[tid + 2 * H_];
      const float hr = s_hW[tid], hz = s_hW[tid + H_], hn = s_hW[tid + 2 * H_];
      const float r = 1.f / (1.f + expf(-(xr + hr)));
      const float z = 1.f / (1.f + expf(-(xz + hz)));
      const float n = tanhf(xn + r * hn);
      const float hp = s_h[cur][tid];
      const float hnew = (1.f - z) * n + z * hp;
      hmax = fmaxf(hmax, hnew);
      s_h[nxt][tid] = hnew;
    }
    __syncthreads();
  }
  if (tid < H_) pooled[((size_t)dir * B_ + b) * H_ + tid] = hmax;
}

// ---------------------------------------------------------------------------
// K4: classifier  out[b][c] = dot(pooled[b], lbl_w[c]) + lbl_b[c]
// ---------------------------------------------------------------------------
__global__ __launch_bounds__(128) void k_cls(
    const float* __restrict__ pooled, const float* __restrict__ lbl_w,
    const float* __restrict__ lbl_b, float* __restrict__ out) {
  const int b = blockIdx.x;
  const int tid = threadIdx.x;
  __shared__ float s_p[2 * H_];
  if (tid < H_) {
    s_p[tid] = pooled[(size_t)b * H_ + tid];                 // forward max
    s_p[tid + H_] = pooled[((size_t)B_ + b) * H_ + tid];     // backward max
  }
  __syncthreads();
  if (tid < C_) {
    float acc = lbl_b[tid];
    const float* wr = lbl_w + (size_t)tid * 2 * H_;
#pragma unroll
    for (int k = 0; k < 2 * H_; ++k) acc += s_p[k] * wr[k];
    out[(size_t)b * C_ + tid] = acc;
  }
}

extern "C" void kernel_launch(void* const* d_in, const int* in_sizes, int n_in,
                              void* d_out, int out_size, void* d_ws,
                              size_t ws_size, hipStream_t stream) {
  const int* tokens = (const int*)d_in[0];
  const int* parents = (const int*)d_in[1];
  const float* emb = (const float*)d_in[2];
  const float* Wc_w = (const float*)d_in[3];
  const float* Wc_b = (const float*)d_in[4];
  const float* Wih_f = (const float*)d_in[5];
  const float* Whh_f = (const float*)d_in[6];
  const float* bih_f = (const float*)d_in[7];
  const float* bhh_f = (const float*)d_in[8];
  const float* Wih_b = (const float*)d_in[9];
  const float* Whh_b = (const float*)d_in[10];
  const float* bih_b = (const float*)d_in[11];
  const float* bhh_b = (const float*)d_in[12];
  const float* lbl_w = (const float*)d_in[13];
  const float* lbl_b = (const float*)d_in[14];
  float* out = (float*)d_out;

  float* enc = (float*)d_ws;                  // T*D        =  8.0 MB
  float* xWf = enc + (size_t)T_ * D_;         // T*G        = 19.7 MB
  float* xWb = xWf + (size_t)T_ * G_;         // T*G        = 19.7 MB
  float* pooled = xWb + (size_t)T_ * G_;      // 2*B*H      =  0.1 MB

  k_tree<<<2048, 128, 0, stream>>>(tokens, parents, emb, Wc_w, Wc_b, enc);
  k_xw<<<T_ / 8, 640, 0, stream>>>(enc, Wih_f, bih_f, Wih_b, bih_b, xWf, xWb);
  k_gru<<<256, 320, 0, stream>>>(xWf, xWb, Whh_f, bhh_f, Whh_b, bhh_b, pooled);
  k_cls<<<B_, 128, 0, stream>>>(pooled, lbl_w, lbl_b, out);
}

// Round 5
// 390.636 us; speedup vs baseline: 1.5032x; 1.5032x over previous
//
#include <hip/hip_runtime.h>
#include <cmath>

#define B_ 128
#define L_ 128
#define N_ 16
#define E_ 128
#define D_ 128
#define H_ 100
#define G_ 300   // 3*H
#define C_ 104
#define T_ (B_*L_)

typedef short bf16x8 __attribute__((ext_vector_type(8)));
typedef float f32x4 __attribute__((ext_vector_type(4)));

__device__ __forceinline__ short f2bf(float f) {
  unsigned u = __builtin_bit_cast(unsigned, f);
  u += 0x7fffu + ((u >> 16) & 1u);   // round-to-nearest-even
  return (short)(u >> 16);
}

// ---------------------------------------------------------------------------
// K1 (MFMA): fused embedding gather + W_c projection (bf16 MFMA, fp32 accum)
//            + bottom-up tree aggregation + node max-pool + relu -> enc[T,D]
// One wave per tree (M=16 nodes). Wc^T lives in 128 VGPRs of bf16 B-frags
// (preloaded once per wave); A-frags gathered straight from global emb.
// mfma_f32_16x16x32_bf16: A row=l&15,k=(l>>4)*8+j; D col=l&15,row=(l>>4)*4+r.
// Epilogue through a per-wave LDS tile (stride 132 -> <=2-way banks). No
// __syncthreads anywhere: each wave owns its LDS region (lockstep safety).
// ---------------------------------------------------------------------------
__global__ __launch_bounds__(256, 2) void k_tree(
    const int* __restrict__ tokens, const int* __restrict__ parents,
    const float* __restrict__ emb, const float* __restrict__ Wc_w,
    const float* __restrict__ Wc_b, float* __restrict__ enc) {
  __shared__ float s_h[4][N_][132];
  __shared__ int s_par[4][N_];
  const int tid = threadIdx.x;
  const int wid = tid >> 6;   // wave within block
  const int l = tid & 63;     // lane
  const int lr = l & 15;      // row (A) / col (B,D) index
  const int lk = l >> 4;      // k-group

  // B-frags: Bf[nt][ks] lane l holds Wc^T[k = ks*32+lk*8+j][n = nt*16+lr]
  //        = Wc_w[nt*16+lr][ks*32+lk*8+j] -> 8 consecutive floats, bf16-RNE.
  bf16x8 Bf[8][4];
#pragma unroll
  for (int nt = 0; nt < 8; ++nt)
#pragma unroll
    for (int ks = 0; ks < 4; ++ks) {
      const float* src = Wc_w + (size_t)(nt * 16 + lr) * E_ + ks * 32 + lk * 8;
      const float4 p0 = *reinterpret_cast<const float4*>(src);
      const float4 p1 = *reinterpret_cast<const float4*>(src + 4);
      bf16x8 v;
      v[0] = f2bf(p0.x); v[1] = f2bf(p0.y); v[2] = f2bf(p0.z); v[3] = f2bf(p0.w);
      v[4] = f2bf(p1.x); v[5] = f2bf(p1.y); v[6] = f2bf(p1.z); v[7] = f2bf(p1.w);
      Bf[nt][ks] = v;
    }
  float Wb[8];
#pragma unroll
  for (int nt = 0; nt < 8; ++nt) Wb[nt] = Wc_b[nt * 16 + lr];

  const int wave_gid = blockIdx.x * 4 + wid;
  const int wave_tot = gridDim.x * 4;

  for (int t = wave_gid; t < T_; t += wave_tot) {
    const int tok = tokens[t * N_ + lr];
    if (lk == 0) s_par[wid][lr] = parents[t * N_ + lr];

    // A-frags: lane l holds emb[tok(row lr)][ks*32 + lk*8 + j]
    const float* arow = emb + (size_t)tok * E_ + lk * 8;
    bf16x8 Af[4];
#pragma unroll
    for (int ks = 0; ks < 4; ++ks) {
      const float4 p0 = *reinterpret_cast<const float4*>(arow + ks * 32);
      const float4 p1 = *reinterpret_cast<const float4*>(arow + ks * 32 + 4);
      bf16x8 v;
      v[0] = f2bf(p0.x); v[1] = f2bf(p0.y); v[2] = f2bf(p0.z); v[3] = f2bf(p0.w);
      v[4] = f2bf(p1.x); v[5] = f2bf(p1.y); v[6] = f2bf(p1.z); v[7] = f2bf(p1.w);
      Af[ks] = v;
    }

    f32x4 acc[8];
#pragma unroll
    for (int nt = 0; nt < 8; ++nt) {
      f32x4 a = {0.f, 0.f, 0.f, 0.f};
#pragma unroll
      for (int ks = 0; ks < 4; ++ks)
        a = __builtin_amdgcn_mfma_f32_16x16x32_bf16(Af[ks], Bf[nt][ks], a, 0, 0, 0);
      acc[nt] = a;
    }

    // scatter to LDS tile (+bias): value (m = lk*4+r, n = nt*16+lr)
#pragma unroll
    for (int nt = 0; nt < 8; ++nt) {
      const float wb = Wb[nt];
#pragma unroll
      for (int r = 0; r < 4; ++r)
        s_h[wid][lk * 4 + r][nt * 16 + lr] = acc[nt][r] + wb;
    }

    // bottom-up aggregation + max + relu; lane owns columns l and l+64
    // (same-wave LDS producer/consumer: lockstep + compiler waitcnt, no barrier)
#pragma unroll
    for (int j = N_ - 1; j >= 1; --j) {
      const int p = s_par[wid][j];
      s_h[wid][p][l]      += s_h[wid][j][l];
      s_h[wid][p][l + 64] += s_h[wid][j][l + 64];
    }
    float m0 = s_h[wid][0][l], m1 = s_h[wid][0][l + 64];
#pragma unroll
    for (int j = 1; j < N_; ++j) {
      m0 = fmaxf(m0, s_h[wid][j][l]);
      m1 = fmaxf(m1, s_h[wid][j][l + 64]);
    }
    enc[(size_t)t * D_ + l]      = fmaxf(m0, 0.f);
    enc[(size_t)t * D_ + l + 64] = fmaxf(m1, 0.f);
  }
}

// ---------------------------------------------------------------------------
// K2: GRU input projections for BOTH directions (unchanged this round)
// ---------------------------------------------------------------------------
__global__ __launch_bounds__(640) void k_xw(
    const float* __restrict__ enc,
    const float* __restrict__ Wih_f, const float* __restrict__ bih_f,
    const float* __restrict__ Wih_b, const float* __restrict__ bih_b,
    float* __restrict__ xWf, float* __restrict__ xWb) {
  __shared__ __align__(16) float s_enc[8][D_];
  const int tid = threadIdx.x;
  const int m0 = blockIdx.x * 8;

  for (int i = tid; i < 8 * D_; i += 640)
    s_enc[i >> 7][i & 127] = enc[(size_t)m0 * D_ + i];

  float4 w[32];
  float bias = 0.f;
  const int g = tid;
  if (g < 2 * G_) {
    const float* Wrow =
        (g < G_) ? (Wih_f + (size_t)g * D_) : (Wih_b + (size_t)(g - G_) * D_);
    const float4* w4 = reinterpret_cast<const float4*>(Wrow);
#pragma unroll
    for (int i = 0; i < 32; ++i) w[i] = w4[i];
    bias = (g < G_) ? bih_f[g] : bih_b[g - G_];
  }
  __syncthreads();
  if (g >= 2 * G_) return;

  float* const dst = (g < G_) ? xWf : xWb;
  const int gg = (g < G_) ? g : g - G_;
#pragma unroll
  for (int mi = 0; mi < 8; ++mi) {
    float a0 = bias, a1 = 0.f;
#pragma unroll
    for (int e0 = 0; e0 < 32; ++e0) {
      const float4 m4 = reinterpret_cast<const float4*>(&s_enc[mi][0])[e0];
      const float4 wv = w[e0];
      a0 += m4.x * wv.x + m4.z * wv.z;
      a1 += m4.y * wv.y + m4.w * wv.w;
    }
    const int m = m0 + mi;
    const int b = m >> 7, l = m & 127;  // m = b*L + l
    dst[((size_t)l * B_ + b) * G_ + gg] = a0 + a1;
  }
}

// ---------------------------------------------------------------------------
// K3: sequential GRU scan (unchanged this round)
// ---------------------------------------------------------------------------
__global__ __launch_bounds__(320) void k_gru(
    const float* __restrict__ xWf, const float* __restrict__ xWb,
    const float* __restrict__ Whh_f, const float* __restrict__ bhh_f,
    const float* __restrict__ Whh_b, const float* __restrict__ bhh_b,
    float* __restrict__ pooled) {
  const int tid = threadIdx.x;
  const int dir = blockIdx.x >> 7;
  const int b = blockIdx.x & 127;
  const float* xW = dir ? xWb : xWf;
  const float* Whh = dir ? Whh_b : Whh_f;
  const float* bhh = dir ? bhh_b : bhh_f;

  __shared__ float s_h[2][H_];
  __shared__ float s_hW[G_];
  __shared__ float s_x[G_];

  float4 w[25];
  float bias = 0.f;
  if (tid < G_) {
    const float4* w4 = reinterpret_cast<const float4*>(Whh + (size_t)tid * H_);
#pragma unroll
    for (int i = 0; i < 25; ++i) w[i] = w4[i];
    bias = bhh[tid];
  }
  if (tid < H_) s_h[0][tid] = 0.f;
  float hmax = -1e30f;
  __syncthreads();

  for (int t = 0; t < L_; ++t) {
    const int tt = dir ? (L_ - 1 - t) : t;
    const int cur = t & 1, nxt = cur ^ 1;
    if (tid < G_) {
      const float x = xW[((size_t)tt * B_ + b) * G_ + tid];  // issue early
      float a0 = bias, a1 = 0.f;
#pragma unroll
      for (int k = 0; k < 25; ++k) {
        const float4 wv = w[k];
        a0 += s_h[cur][4 * k + 0] * wv.x + s_h[cur][4 * k + 2] * wv.z;
        a1 += s_h[cur][4 * k + 1] * wv.y + s_h[cur][4 * k + 3] * wv.w;
      }
      s_hW[tid] = a0 + a1;
      s_x[tid] = x;
    }
    __syncthreads();
    if (tid < H_) {
      const float xr = s_x[tid], xz = s_x[tid + H_], xn = s_x[tid + 2 * H_];
      const float hr = s_hW[tid], hz = s_hW[tid + H_], hn = s_hW[tid + 2 * H_];
      const float r = 1.f / (1.f + expf(-(xr + hr)));
      const float z = 1.f / (1.f + expf(-(xz + hz)));
      const float n = tanhf(xn + r * hn);
      const float hp = s_h[cur][tid];
      const float hnew = (1.f - z) * n + z * hp;
      hmax = fmaxf(hmax, hnew);
      s_h[nxt][tid] = hnew;
    }
    __syncthreads();
  }
  if (tid < H_) pooled[((size_t)dir * B_ + b) * H_ + tid] = hmax;
}

// ---------------------------------------------------------------------------
// K4: classifier (unchanged this round)
// ---------------------------------------------------------------------------
__global__ __launch_bounds__(128) void k_cls(
    const float* __restrict__ pooled, const float* __restrict__ lbl_w,
    const float* __restrict__ lbl_b, float* __restrict__ out) {
  const int b = blockIdx.x;
  const int tid = threadIdx.x;
  __shared__ float s_p[2 * H_];
  if (tid < H_) {
    s_p[tid] = pooled[(size_t)b * H_ + tid];
    s_p[tid + H_] = pooled[((size_t)B_ + b) * H_ + tid];
  }
  __syncthreads();
  if (tid < C_) {
    float acc = lbl_b[tid];
    const float* wr = lbl_w + (size_t)tid * 2 * H_;
#pragma unroll
    for (int k = 0; k < 2 * H_; ++k) acc += s_p[k] * wr[k];
    out[(size_t)b * C_ + tid] = acc;
  }
}

extern "C" void kernel_launch(void* const* d_in, const int* in_sizes, int n_in,
                              void* d_out, int out_size, void* d_ws,
                              size_t ws_size, hipStream_t stream) {
  const int* tokens = (const int*)d_in[0];
  const int* parents = (const int*)d_in[1];
  const float* emb = (const float*)d_in[2];
  const float* Wc_w = (const float*)d_in[3];
  const float* Wc_b = (const float*)d_in[4];
  const float* Wih_f = (const float*)d_in[5];
  const float* Whh_f = (const float*)d_in[6];
  const float* bih_f = (const float*)d_in[7];
  const float* bhh_f = (const float*)d_in[8];
  const float* Wih_b = (const float*)d_in[9];
  const float* Whh_b = (const float*)d_in[10];
  const float* bih_b = (const float*)d_in[11];
  const float* bhh_b = (const float*)d_in[12];
  const float* lbl_w = (const float*)d_in[13];
  const float* lbl_b = (const float*)d_in[14];
  float* out = (float*)d_out;

  float* enc = (float*)d_ws;                  // T*D        =  8.0 MB
  float* xWf = enc + (size_t)T_ * D_;         // T*G        = 19.7 MB
  float* xWb = xWf + (size_t)T_ * G_;         // T*G        = 19.7 MB
  float* pooled = xWb + (size_t)T_ * G_;      // 2*B*H      =  0.1 MB

  k_tree<<<512, 256, 0, stream>>>(tokens, parents, emb, Wc_w, Wc_b, enc);
  k_xw<<<T_ / 8, 640, 0, stream>>>(enc, Wih_f, bih_f, Wih_b, bih_b, xWf, xWb);
  k_gru<<<256, 320, 0, stream>>>(xWf, xWb, Whh_f, bhh_f, Whh_b, bhh_b, pooled);
  k_cls<<<B_, 128, 0, stream>>>(pooled, lbl_w, lbl_b, out);
}

// Round 6
// 346.923 us; speedup vs baseline: 1.6926x; 1.1260x over previous
//
#include <hip/hip_runtime.h>
#include <cmath>

#define B_ 128
#define L_ 128
#define N_ 16
#define E_ 128
#define D_ 128
#define H_ 100
#define G_ 300   // 3*H
#define C_ 104
#define T_ (B_*L_)

typedef short bf16x8 __attribute__((ext_vector_type(8)));
typedef float f32x4 __attribute__((ext_vector_type(4)));

__device__ __forceinline__ short f2bf(float f) {
  unsigned u = __builtin_bit_cast(unsigned, f);
  u += 0x7fffu + ((u >> 16) & 1u);   // round-to-nearest-even
  return (short)(u >> 16);
}

// ---------------------------------------------------------------------------
// K1 (MFMA): fused embedding gather + W_c projection (bf16 MFMA, fp32 accum)
//            + bottom-up tree aggregation + node max-pool + relu -> enc[T,D]
// (unchanged from round 5 — dropped out of top-5 at ~<139us)
// ---------------------------------------------------------------------------
__global__ __launch_bounds__(256, 2) void k_tree(
    const int* __restrict__ tokens, const int* __restrict__ parents,
    const float* __restrict__ emb, const float* __restrict__ Wc_w,
    const float* __restrict__ Wc_b, float* __restrict__ enc) {
  __shared__ float s_h[4][N_][132];
  __shared__ int s_par[4][N_];
  const int tid = threadIdx.x;
  const int wid = tid >> 6;   // wave within block
  const int l = tid & 63;     // lane
  const int lr = l & 15;      // row (A) / col (B,D) index
  const int lk = l >> 4;      // k-group

  bf16x8 Bf[8][4];
#pragma unroll
  for (int nt = 0; nt < 8; ++nt)
#pragma unroll
    for (int ks = 0; ks < 4; ++ks) {
      const float* src = Wc_w + (size_t)(nt * 16 + lr) * E_ + ks * 32 + lk * 8;
      const float4 p0 = *reinterpret_cast<const float4*>(src);
      const float4 p1 = *reinterpret_cast<const float4*>(src + 4);
      bf16x8 v;
      v[0] = f2bf(p0.x); v[1] = f2bf(p0.y); v[2] = f2bf(p0.z); v[3] = f2bf(p0.w);
      v[4] = f2bf(p1.x); v[5] = f2bf(p1.y); v[6] = f2bf(p1.z); v[7] = f2bf(p1.w);
      Bf[nt][ks] = v;
    }
  float Wb[8];
#pragma unroll
  for (int nt = 0; nt < 8; ++nt) Wb[nt] = Wc_b[nt * 16 + lr];

  const int wave_gid = blockIdx.x * 4 + wid;
  const int wave_tot = gridDim.x * 4;

  for (int t = wave_gid; t < T_; t += wave_tot) {
    const int tok = tokens[t * N_ + lr];
    if (lk == 0) s_par[wid][lr] = parents[t * N_ + lr];

    const float* arow = emb + (size_t)tok * E_ + lk * 8;
    bf16x8 Af[4];
#pragma unroll
    for (int ks = 0; ks < 4; ++ks) {
      const float4 p0 = *reinterpret_cast<const float4*>(arow + ks * 32);
      const float4 p1 = *reinterpret_cast<const float4*>(arow + ks * 32 + 4);
      bf16x8 v;
      v[0] = f2bf(p0.x); v[1] = f2bf(p0.y); v[2] = f2bf(p0.z); v[3] = f2bf(p0.w);
      v[4] = f2bf(p1.x); v[5] = f2bf(p1.y); v[6] = f2bf(p1.z); v[7] = f2bf(p1.w);
      Af[ks] = v;
    }

    f32x4 acc[8];
#pragma unroll
    for (int nt = 0; nt < 8; ++nt) {
      f32x4 a = {0.f, 0.f, 0.f, 0.f};
#pragma unroll
      for (int ks = 0; ks < 4; ++ks)
        a = __builtin_amdgcn_mfma_f32_16x16x32_bf16(Af[ks], Bf[nt][ks], a, 0, 0, 0);
      acc[nt] = a;
    }

#pragma unroll
    for (int nt = 0; nt < 8; ++nt) {
      const float wb = Wb[nt];
#pragma unroll
      for (int r = 0; r < 4; ++r)
        s_h[wid][lk * 4 + r][nt * 16 + lr] = acc[nt][r] + wb;
    }

#pragma unroll
    for (int j = N_ - 1; j >= 1; --j) {
      const int p = s_par[wid][j];
      s_h[wid][p][l]      += s_h[wid][j][l];
      s_h[wid][p][l + 64] += s_h[wid][j][l + 64];
    }
    float m0 = s_h[wid][0][l], m1 = s_h[wid][0][l + 64];
#pragma unroll
    for (int j = 1; j < N_; ++j) {
      m0 = fmaxf(m0, s_h[wid][j][l]);
      m1 = fmaxf(m1, s_h[wid][j][l + 64]);
    }
    enc[(size_t)t * D_ + l]      = fmaxf(m0, 0.f);
    enc[(size_t)t * D_ + l + 64] = fmaxf(m1, 0.f);
  }
}

// ---------------------------------------------------------------------------
// K2: GRU input projections (unchanged this round; suspect same 64-VGPR
//     rematerialization trap — attack next round with counter evidence)
// ---------------------------------------------------------------------------
__global__ __launch_bounds__(640) void k_xw(
    const float* __restrict__ enc,
    const float* __restrict__ Wih_f, const float* __restrict__ bih_f,
    const float* __restrict__ Wih_b, const float* __restrict__ bih_b,
    float* __restrict__ xWf, float* __restrict__ xWb) {
  __shared__ __align__(16) float s_enc[8][D_];
  const int tid = threadIdx.x;
  const int m0 = blockIdx.x * 8;

  for (int i = tid; i < 8 * D_; i += 640)
    s_enc[i >> 7][i & 127] = enc[(size_t)m0 * D_ + i];

  float4 w[32];
  float bias = 0.f;
  const int g = tid;
  if (g < 2 * G_) {
    const float* Wrow =
        (g < G_) ? (Wih_f + (size_t)g * D_) : (Wih_b + (size_t)(g - G_) * D_);
    const float4* w4 = reinterpret_cast<const float4*>(Wrow);
#pragma unroll
    for (int i = 0; i < 32; ++i) w[i] = w4[i];
    bias = (g < G_) ? bih_f[g] : bih_b[g - G_];
  }
  __syncthreads();
  if (g >= 2 * G_) return;

  float* const dst = (g < G_) ? xWf : xWb;
  const int gg = (g < G_) ? g : g - G_;
#pragma unroll
  for (int mi = 0; mi < 8; ++mi) {
    float a0 = bias, a1 = 0.f;
#pragma unroll
    for (int e0 = 0; e0 < 32; ++e0) {
      const float4 m4 = reinterpret_cast<const float4*>(&s_enc[mi][0])[e0];
      const float4 wv = w[e0];
      a0 += m4.x * wv.x + m4.z * wv.z;
      a1 += m4.y * wv.y + m4.w * wv.w;
    }
    const int m = m0 + mi;
    const int b = m >> 7, l = m & 127;  // m = b*L + l
    dst[((size_t)l * B_ + b) * G_ + gg] = a0 + a1;
  }
}

// ---------------------------------------------------------------------------
// K3 (v2): sequential GRU scan. One block per (dir, batch) = 256 blocks.
// FIX for round-5 finding: v1's float4 w[25] (100 floats) exceeded the
// compiler's 64-VGPR budget -> Whh re-loaded from L2 every step (~3.9 GB
// L2 traffic ~= the whole 139us). v2: 600 workers, 2 per g-row (52/48
// split, both halves 16B-aligned), <=13 float4 = 52 weight VGPRs per
// thread, __launch_bounds__(640,2) -> register-resident.
// Also: next-step xW prefetch into regs (hide global latency under the
// worker phase) and __expf-based sigmoid/tanh (v_exp_f32, not ocml tanhf).
// ---------------------------------------------------------------------------
__global__ __launch_bounds__(640, 2) void k_gru(
    const float* __restrict__ xWf, const float* __restrict__ xWb,
    const float* __restrict__ Whh_f, const float* __restrict__ bhh_f,
    const float* __restrict__ Whh_b, const float* __restrict__ bhh_b,
    float* __restrict__ pooled) {
  const int tid = threadIdx.x;
  const int dir = blockIdx.x >> 7;
  const int b = blockIdx.x & 127;
  const float* xW = dir ? xWb : xWf;
  const float* Whh = dir ? Whh_b : Whh_f;
  const float* bhh = dir ? bhh_b : bhh_f;

  __shared__ __align__(16) float s_h[2][104];   // h double-buffer (100 used)
  __shared__ float s_part[2][304];              // per-half partial dots

  const bool worker = tid < 2 * G_;
  const int g = worker ? (tid % G_) : 0;        // g-row 0..299
  const int half = worker ? (tid / G_) : 0;     // 0: k 0..51, 1: k 52..99
  const int k0 = half * 52;
  const int nf = half ? 12 : 13;                // float4 chunks this half

  // Whh[g][k0 .. k0+4*nf-1] -> registers (16B-aligned: 400g and 400g+208)
  float4 wv[13];
  if (worker) {
    const float4* wr = reinterpret_cast<const float4*>(Whh + (size_t)g * H_ + k0);
#pragma unroll
    for (int i = 0; i < 13; ++i)
      if (i < nf) wv[i] = wr[i];
  }

  // activation-thread state (tid < 100): biases + x for step 0
  float br = 0.f, bz = 0.f, bn = 0.f, xr = 0.f, xz = 0.f, xn = 0.f;
  if (tid < H_) {
    br = bhh[tid]; bz = bhh[tid + H_]; bn = bhh[tid + 2 * H_];
    const int t0 = dir ? (L_ - 1) : 0;
    const float* xp = xW + ((size_t)t0 * B_ + b) * G_;
    xr = xp[tid]; xz = xp[tid + H_]; xn = xp[tid + 2 * H_];
  }
  if (tid < 104) { s_h[0][tid] = 0.f; s_h[1][tid] = 0.f; }
  float hmax = -1e30f;
  __syncthreads();

  for (int t = 0; t < L_; ++t) {
    const int cur = t & 1, nxt = cur ^ 1;

    // prefetch next step's x (in flight during worker phase + barrier)
    float xr_n = 0.f, xz_n = 0.f, xn_n = 0.f;
    if (tid < H_ && t + 1 < L_) {
      const int tt = dir ? (L_ - 2 - t) : (t + 1);
      const float* xp = xW + ((size_t)tt * B_ + b) * G_;
      xr_n = xp[tid]; xz_n = xp[tid + H_]; xn_n = xp[tid + 2 * H_];
    }

    if (worker) {  // partial dot: wave-broadcast LDS float4 reads, 4 accums
      const float4* hv = reinterpret_cast<const float4*>(&s_h[cur][k0]);
      float a0 = 0.f, a1 = 0.f, a2 = 0.f, a3 = 0.f;
#pragma unroll
      for (int i = 0; i < 13; ++i)
        if (i < nf) {
          const float4 h4 = hv[i];
          a0 += h4.x * wv[i].x; a1 += h4.y * wv[i].y;
          a2 += h4.z * wv[i].z; a3 += h4.w * wv[i].w;
        }
      s_part[half][g] = (a0 + a1) + (a2 + a3);
    }
    __syncthreads();

    if (tid < H_) {
      const float hr = s_part[0][tid]          + s_part[1][tid]          + br;
      const float hz = s_part[0][tid + H_]     + s_part[1][tid + H_]     + bz;
      const float hn = s_part[0][tid + 2 * H_] + s_part[1][tid + 2 * H_] + bn;
      const float r = 1.f / (1.f + __expf(-(xr + hr)));
      const float z = 1.f / (1.f + __expf(-(xz + hz)));
      const float e2 = __expf(2.f * (xn + r * hn));
      const float n = 1.f - 2.f / (e2 + 1.f);        // tanh, overflow-safe
      const float hp = s_h[cur][tid];
      const float hnew = (1.f - z) * n + z * hp;
      hmax = fmaxf(hmax, hnew);
      s_h[nxt][tid] = hnew;
      xr = xr_n; xz = xz_n; xn = xn_n;
    }
    __syncthreads();
  }
  if (tid < H_) pooled[((size_t)dir * B_ + b) * H_ + tid] = hmax;
}

// ---------------------------------------------------------------------------
// K4: classifier (unchanged)
// ---------------------------------------------------------------------------
__global__ __launch_bounds__(128) void k_cls(
    const float* __restrict__ pooled, const float* __restrict__ lbl_w,
    const float* __restrict__ lbl_b, float* __restrict__ out) {
  const int b = blockIdx.x;
  const int tid = threadIdx.x;
  __shared__ float s_p[2 * H_];
  if (tid < H_) {
    s_p[tid] = pooled[(size_t)b * H_ + tid];
    s_p[tid + H_] = pooled[((size_t)B_ + b) * H_ + tid];
  }
  __syncthreads();
  if (tid < C_) {
    float acc = lbl_b[tid];
    const float* wr = lbl_w + (size_t)tid * 2 * H_;
#pragma unroll
    for (int k = 0; k < 2 * H_; ++k) acc += s_p[k] * wr[k];
    out[(size_t)b * C_ + tid] = acc;
  }
}

extern "C" void kernel_launch(void* const* d_in, const int* in_sizes, int n_in,
                              void* d_out, int out_size, void* d_ws,
                              size_t ws_size, hipStream_t stream) {
  const int* tokens = (const int*)d_in[0];
  const int* parents = (const int*)d_in[1];
  const float* emb = (const float*)d_in[2];
  const float* Wc_w = (const float*)d_in[3];
  const float* Wc_b = (const float*)d_in[4];
  const float* Wih_f = (const float*)d_in[5];
  const float* Whh_f = (const float*)d_in[6];
  const float* bih_f = (const float*)d_in[7];
  const float* bhh_f = (const float*)d_in[8];
  const float* Wih_b = (const float*)d_in[9];
  const float* Whh_b = (const float*)d_in[10];
  const float* bih_b = (const float*)d_in[11];
  const float* bhh_b = (const float*)d_in[12];
  const float* lbl_w = (const float*)d_in[13];
  const float* lbl_b = (const float*)d_in[14];
  float* out = (float*)d_out;

  float* enc = (float*)d_ws;                  // T*D        =  8.0 MB
  float* xWf = enc + (size_t)T_ * D_;         // T*G        = 19.7 MB
  float* xWb = xWf + (size_t)T_ * G_;         // T*G        = 19.7 MB
  float* pooled = xWb + (size_t)T_ * G_;      // 2*B*H      =  0.1 MB

  k_tree<<<512, 256, 0, stream>>>(tokens, parents, emb, Wc_w, Wc_b, enc);
  k_xw<<<T_ / 8, 640, 0, stream>>>(enc, Wih_f, bih_f, Wih_b, bih_b, xWf, xWb);
  k_gru<<<256, 640, 0, stream>>>(xWf, xWb, Whh_f, bhh_f, Whh_b, bhh_b, pooled);
  k_cls<<<B_, 128, 0, stream>>>(pooled, lbl_w, lbl_b, out);
}

// Round 11
// 249.368 us; speedup vs baseline: 2.3547x; 1.3912x over previous
//
#include <hip/hip_runtime.h>
#include <cmath>

#define B_ 128
#define L_ 128
#define N_ 16
#define E_ 128
#define D_ 128
#define H_ 100
#define G_ 300   // 3*H
#define C_ 104
#define T_ (B_*L_)
#define XST 600  // xW row stride (cols 0..299 fwd, 300..599 bwd)

typedef short bf16x8 __attribute__((ext_vector_type(8)));
typedef float f32x4 __attribute__((ext_vector_type(4)));

__device__ __forceinline__ short f2bf(float f) {
  unsigned u = __builtin_bit_cast(unsigned, f);
  u += 0x7fffu + ((u >> 16) & 1u);   // round-to-nearest-even
  return (short)(u >> 16);
}

// ---------------------------------------------------------------------------
// K1 (MFMA): fused embedding gather + W_c projection + tree agg + max/relu
// (unchanged from round 5)
// ---------------------------------------------------------------------------
__global__ __launch_bounds__(256, 2) void k_tree(
    const int* __restrict__ tokens, const int* __restrict__ parents,
    const float* __restrict__ emb, const float* __restrict__ Wc_w,
    const float* __restrict__ Wc_b, float* __restrict__ enc) {
  __shared__ float s_h[4][N_][132];
  __shared__ int s_par[4][N_];
  const int tid = threadIdx.x;
  const int wid = tid >> 6;
  const int l = tid & 63;
  const int lr = l & 15;
  const int lk = l >> 4;

  bf16x8 Bf[8][4];
#pragma unroll
  for (int nt = 0; nt < 8; ++nt)
#pragma unroll
    for (int ks = 0; ks < 4; ++ks) {
      const float* src = Wc_w + (size_t)(nt * 16 + lr) * E_ + ks * 32 + lk * 8;
      const float4 p0 = *reinterpret_cast<const float4*>(src);
      const float4 p1 = *reinterpret_cast<const float4*>(src + 4);
      bf16x8 v;
      v[0] = f2bf(p0.x); v[1] = f2bf(p0.y); v[2] = f2bf(p0.z); v[3] = f2bf(p0.w);
      v[4] = f2bf(p1.x); v[5] = f2bf(p1.y); v[6] = f2bf(p1.z); v[7] = f2bf(p1.w);
      Bf[nt][ks] = v;
    }
  float Wb[8];
#pragma unroll
  for (int nt = 0; nt < 8; ++nt) Wb[nt] = Wc_b[nt * 16 + lr];

  const int wave_gid = blockIdx.x * 4 + wid;
  const int wave_tot = gridDim.x * 4;

  for (int t = wave_gid; t < T_; t += wave_tot) {
    const int tok = tokens[t * N_ + lr];
    if (lk == 0) s_par[wid][lr] = parents[t * N_ + lr];

    const float* arow = emb + (size_t)tok * E_ + lk * 8;
    bf16x8 Af[4];
#pragma unroll
    for (int ks = 0; ks < 4; ++ks) {
      const float4 p0 = *reinterpret_cast<const float4*>(arow + ks * 32);
      const float4 p1 = *reinterpret_cast<const float4*>(arow + ks * 32 + 4);
      bf16x8 v;
      v[0] = f2bf(p0.x); v[1] = f2bf(p0.y); v[2] = f2bf(p0.z); v[3] = f2bf(p0.w);
      v[4] = f2bf(p1.x); v[5] = f2bf(p1.y); v[6] = f2bf(p1.z); v[7] = f2bf(p1.w);
      Af[ks] = v;
    }

    f32x4 acc[8];
#pragma unroll
    for (int nt = 0; nt < 8; ++nt) {
      f32x4 a = {0.f, 0.f, 0.f, 0.f};
#pragma unroll
      for (int ks = 0; ks < 4; ++ks)
        a = __builtin_amdgcn_mfma_f32_16x16x32_bf16(Af[ks], Bf[nt][ks], a, 0, 0, 0);
      acc[nt] = a;
    }

#pragma unroll
    for (int nt = 0; nt < 8; ++nt) {
      const float wb = Wb[nt];
#pragma unroll
      for (int r = 0; r < 4; ++r)
        s_h[wid][lk * 4 + r][nt * 16 + lr] = acc[nt][r] + wb;
    }

#pragma unroll
    for (int j = N_ - 1; j >= 1; --j) {
      const int p = s_par[wid][j];
      s_h[wid][p][l]      += s_h[wid][j][l];
      s_h[wid][p][l + 64] += s_h[wid][j][l + 64];
    }
    float m0 = s_h[wid][0][l], m1 = s_h[wid][0][l + 64];
#pragma unroll
    for (int j = 1; j < N_; ++j) {
      m0 = fmaxf(m0, s_h[wid][j][l]);
      m1 = fmaxf(m1, s_h[wid][j][l + 64]);
    }
    enc[(size_t)t * D_ + l]      = fmaxf(m0, 0.f);
    enc[(size_t)t * D_ + l + 64] = fmaxf(m1, 0.f);
  }
}

// ---------------------------------------------------------------------------
// K2 (v2, MFMA): xW[m][n] = enc[m][:] . Wcat[n][:] + bihcat[n]
// m = b*L+l (0..16383), n = 0..599 (n<300 fwd g, >=300 bwd g-300).
// FIX for round-6 finding: v1's float4 w[32] (128 floats) overflowed the
// VGPR budget (VGPR_Count=76) -> Wih re-streamed from L2 every mi iter
// (~5 GB ~= the whole 137us). v2: MFMA GEMM, wave owns 4 n-tiles of
// B-frags (64 VGPR, register-resident by construction), loops 8 m-tiles.
// Same verified fragment mapping as k_tree. N padded to 608: OOB rows
// clamped on load, lanes masked on store. Bias fused at store.
// ---------------------------------------------------------------------------
__global__ __launch_bounds__(256, 2) void k_xw(
    const float* __restrict__ enc,
    const float* __restrict__ Wih_f, const float* __restrict__ bih_f,
    const float* __restrict__ Wih_b, const float* __restrict__ bih_b,
    float* __restrict__ xW) {
  const int tid = threadIdx.x;
  const int wid = tid >> 6, l = tid & 63;
  const int lr = l & 15, lk = l >> 4;
  const int wave_gid = blockIdx.x * 4 + wid;   // 0..1279
  const int ns = wave_gid / 128;               // n-slice 0..9 (4 n-tiles each)
  const int mg = wave_gid % 128;               // m-group

  bf16x8 Bf[4][4];
  float bi[4];
  bool valid[4];
#pragma unroll
  for (int i = 0; i < 4; ++i) {
    const int n = (ns * 4 + i) * 16 + lr;
    valid[i] = (n < XST);
    const int nc = valid[i] ? n : (XST - 1);   // clamp: no OOB reads
    const float* Wrow = (nc < G_) ? Wih_f + (size_t)nc * D_
                                  : Wih_b + (size_t)(nc - G_) * D_;
    bi[i] = (nc < G_) ? bih_f[nc] : bih_b[nc - G_];
#pragma unroll
    for (int ks = 0; ks < 4; ++ks) {
      const float* src = Wrow + ks * 32 + lk * 8;
      const float4 p0 = *reinterpret_cast<const float4*>(src);
      const float4 p1 = *reinterpret_cast<const float4*>(src + 4);
      bf16x8 v;
      v[0] = f2bf(p0.x); v[1] = f2bf(p0.y); v[2] = f2bf(p0.z); v[3] = f2bf(p0.w);
      v[4] = f2bf(p1.x); v[5] = f2bf(p1.y); v[6] = f2bf(p1.z); v[7] = f2bf(p1.w);
      Bf[i][ks] = v;
    }
  }

  for (int mt = mg; mt < T_ / 16; mt += 128) {
    const float* arow = enc + (size_t)(mt * 16 + lr) * D_ + lk * 8;
    bf16x8 Af[4];
#pragma unroll
    for (int ks = 0; ks < 4; ++ks) {
      const float4 p0 = *reinterpret_cast<const float4*>(arow + ks * 32);
      const float4 p1 = *reinterpret_cast<const float4*>(arow + ks * 32 + 4);
      bf16x8 v;
      v[0] = f2bf(p0.x); v[1] = f2bf(p0.y); v[2] = f2bf(p0.z); v[3] = f2bf(p0.w);
      v[4] = f2bf(p1.x); v[5] = f2bf(p1.y); v[6] = f2bf(p1.z); v[7] = f2bf(p1.w);
      Af[ks] = v;
    }

#pragma unroll
    for (int i = 0; i < 4; ++i) {
      f32x4 a = {0.f, 0.f, 0.f, 0.f};
#pragma unroll
      for (int ks = 0; ks < 4; ++ks)
        a = __builtin_amdgcn_mfma_f32_16x16x32_bf16(Af[ks], Bf[i][ks], a, 0, 0, 0);
      if (valid[i]) {
        const int n = (ns * 4 + i) * 16 + lr;
        float* dst = xW + (size_t)(mt * 16 + lk * 4) * XST + n;
#pragma unroll
        for (int r = 0; r < 4; ++r) dst[r * XST] = a[r] + bi[i];
      }
    }
  }
}

// ---------------------------------------------------------------------------
// K3 (v2): sequential GRU scan (round-6 structure; reads from new xW layout:
// row = b*L + t, col = dir*300 + g)
// ---------------------------------------------------------------------------
__global__ __launch_bounds__(640, 2) void k_gru(
    const float* __restrict__ xW,
    const float* __restrict__ Whh_f, const float* __restrict__ bhh_f,
    const float* __restrict__ Whh_b, const float* __restrict__ bhh_b,
    float* __restrict__ pooled) {
  const int tid = threadIdx.x;
  const int dir = blockIdx.x >> 7;
  const int b = blockIdx.x & 127;
  const float* Whh = dir ? Whh_b : Whh_f;
  const float* bhh = dir ? bhh_b : bhh_f;
  const float* xrow0 = xW + (size_t)b * L_ * XST + dir * G_;

  __shared__ __align__(16) float s_h[2][104];
  __shared__ float s_part[2][304];

  const bool worker = tid < 2 * G_;
  const int g = worker ? (tid % G_) : 0;
  const int half = worker ? (tid / G_) : 0;
  const int k0 = half * 52;
  const int nf = half ? 12 : 13;

  float4 wv[13];
  if (worker) {
    const float4* wr = reinterpret_cast<const float4*>(Whh + (size_t)g * H_ + k0);
#pragma unroll
    for (int i = 0; i < 13; ++i)
      if (i < nf) wv[i] = wr[i];
  }

  float br = 0.f, bz = 0.f, bn = 0.f, xr = 0.f, xz = 0.f, xn = 0.f;
  if (tid < H_) {
    br = bhh[tid]; bz = bhh[tid + H_]; bn = bhh[tid + 2 * H_];
    const int t0 = dir ? (L_ - 1) : 0;
    const float* xp = xrow0 + (size_t)t0 * XST;
    xr = xp[tid]; xz = xp[tid + H_]; xn = xp[tid + 2 * H_];
  }
  if (tid < 104) { s_h[0][tid] = 0.f; s_h[1][tid] = 0.f; }
  float hmax = -1e30f;
  __syncthreads();

  for (int t = 0; t < L_; ++t) {
    const int cur = t & 1, nxt = cur ^ 1;

    float xr_n = 0.f, xz_n = 0.f, xn_n = 0.f;
    if (tid < H_ && t + 1 < L_) {
      const int tt = dir ? (L_ - 2 - t) : (t + 1);
      const float* xp = xrow0 + (size_t)tt * XST;
      xr_n = xp[tid]; xz_n = xp[tid + H_]; xn_n = xp[tid + 2 * H_];
    }

    if (worker) {
      const float4* hv = reinterpret_cast<const float4*>(&s_h[cur][k0]);
      float a0 = 0.f, a1 = 0.f, a2 = 0.f, a3 = 0.f;
#pragma unroll
      for (int i = 0; i < 13; ++i)
        if (i < nf) {
          const float4 h4 = hv[i];
          a0 += h4.x * wv[i].x; a1 += h4.y * wv[i].y;
          a2 += h4.z * wv[i].z; a3 += h4.w * wv[i].w;
        }
      s_part[half][g] = (a0 + a1) + (a2 + a3);
    }
    __syncthreads();

    if (tid < H_) {
      const float hr = s_part[0][tid]          + s_part[1][tid]          + br;
      const float hz = s_part[0][tid + H_]     + s_part[1][tid + H_]     + bz;
      const float hn = s_part[0][tid + 2 * H_] + s_part[1][tid + 2 * H_] + bn;
      const float r = 1.f / (1.f + __expf(-(xr + hr)));
      const float z = 1.f / (1.f + __expf(-(xz + hz)));
      const float e2 = __expf(2.f * (xn + r * hn));
      const float n = 1.f - 2.f / (e2 + 1.f);
      const float hp = s_h[cur][tid];
      const float hnew = (1.f - z) * n + z * hp;
      hmax = fmaxf(hmax, hnew);
      s_h[nxt][tid] = hnew;
      xr = xr_n; xz = xz_n; xn = xn_n;
    }
    __syncthreads();
  }
  if (tid < H_) pooled[((size_t)dir * B_ + b) * H_ + tid] = hmax;
}

// ---------------------------------------------------------------------------
// K4: classifier (unchanged)
// ---------------------------------------------------------------------------
__global__ __launch_bounds__(128) void k_cls(
    const float* __restrict__ pooled, const float* __restrict__ lbl_w,
    const float* __restrict__ lbl_b, float* __restrict__ out) {
  const int b = blockIdx.x;
  const int tid = threadIdx.x;
  __shared__ float s_p[2 * H_];
  if (tid < H_) {
    s_p[tid] = pooled[(size_t)b * H_ + tid];
    s_p[tid + H_] = pooled[((size_t)B_ + b) * H_ + tid];
  }
  __syncthreads();
  if (tid < C_) {
    float acc = lbl_b[tid];
    const float* wr = lbl_w + (size_t)tid * 2 * H_;
#pragma unroll
    for (int k = 0; k < 2 * H_; ++k) acc += s_p[k] * wr[k];
    out[(size_t)b * C_ + tid] = acc;
  }
}

extern "C" void kernel_launch(void* const* d_in, const int* in_sizes, int n_in,
                              void* d_out, int out_size, void* d_ws,
                              size_t ws_size, hipStream_t stream) {
  const int* tokens = (const int*)d_in[0];
  const int* parents = (const int*)d_in[1];
  const float* emb = (const float*)d_in[2];
  const float* Wc_w = (const float*)d_in[3];
  const float* Wc_b = (const float*)d_in[4];
  const float* Wih_f = (const float*)d_in[5];
  const float* Whh_f = (const float*)d_in[6];
  const float* bih_f = (const float*)d_in[7];
  const float* bhh_f = (const float*)d_in[8];
  const float* Wih_b = (const float*)d_in[9];
  const float* Whh_b = (const float*)d_in[10];
  const float* bih_b = (const float*)d_in[11];
  const float* bhh_b = (const float*)d_in[12];
  const float* lbl_w = (const float*)d_in[13];
  const float* lbl_b = (const float*)d_in[14];
  float* out = (float*)d_out;

  float* enc = (float*)d_ws;                  // T*D         =  8.0 MB
  float* xW = enc + (size_t)T_ * D_;          // T*600       = 37.5 MB
  float* pooled = xW + (size_t)T_ * XST;      // 2*B*H       =  0.1 MB

  k_tree<<<512, 256, 0, stream>>>(tokens, parents, emb, Wc_w, Wc_b, enc);
  k_xw<<<320, 256, 0, stream>>>(enc, Wih_f, bih_f, Wih_b, bih_b, xW);
  k_gru<<<256, 640, 0, stream>>>(xW, Whh_f, bhh_f, Whh_b, bhh_b, pooled);
  k_cls<<<B_, 128, 0, stream>>>(pooled, lbl_w, lbl_b, out);
}